// Round 1
// 2085.753 us; speedup vs baseline: 1.0286x; 1.0286x over previous
//
#include <hip/hip_runtime.h>

// Problem constants
#define B_TOK 8192
#define D_DIM 1024
#define H_DIM 4096
#define E_NUM 8
#define C_DIM 1024

typedef unsigned short ushort_t;
typedef __attribute__((ext_vector_type(8))) short bf16x8;   // 8 bf16 = 4 VGPRs
typedef __attribute__((ext_vector_type(4))) float f32x4;    // MFMA acc

// round-to-nearest-even fp32 -> bf16
__device__ inline ushort_t f2bf(float f) {
    unsigned u = __float_as_uint(f);
    unsigned r = (u + 0x7fffu + ((u >> 16) & 1u)) >> 16;
    return (ushort_t)r;
}

// async global->LDS, 16B per lane. HW dest = wave-uniform base + lane*16.
__device__ inline void async16(const ushort_t* g, void* l) {
    __builtin_amdgcn_global_load_lds((__attribute__((address_space(1))) void*)g,
                                     (__attribute__((address_space(3))) void*)l,
                                     16, 0, 0);
}

#define FENCE() asm volatile("" ::: "memory")
#define BARRIER() do { FENCE(); __builtin_amdgcn_s_barrier(); FENCE(); } while (0)
#define WAITLGKM0() asm volatile("s_waitcnt lgkmcnt(0)" ::: "memory")
#define WAITVM4()   asm volatile("s_waitcnt vmcnt(4)" ::: "memory")

// ===========================================================================
// 256x256 8-phase bf16 GEMM (T2 swizzle + T3/T4 counted vmcnt + T5 setprio)
// C = relu(A[M,K] @ Bt[N,K]^T + bias) -> bf16, row stride ldc.
// 512 thr = 8 waves (2M x 4N); per-wave 128x64 out; BK=64; LDS 128 KiB dbuf.
//
// LDS layout per tile buf: [256 rows][64 bf16] with XOR swizzle:
//   phys 16B-chunk = logical chunk ^ (row & 7)   (chunk = k>>3 within tile)
// Staged via global_load_lds (linear dest) with pre-swizzled global source.
//
// Phase schedule per iteration (2 K-tiles: even->buf0, odd->buf1):
//   ph1: rd A.mq0+B.nq0(buf0) | stage T+1.A.h0->buf1 | bar | mfma(0,0) | bar
//   ph2: rd B.nq1(buf0)       | stage T+1.A.h1->buf1 | bar | mfma(0,1) | bar
//   ph3: rd A.mq1(buf0)       | stage T+2.B.h0->buf0 | bar | mfma(1,1) | bar
//   ph4:                      | stage T+2.B.h1->buf0 | bar | mfma(1,0) | vmcnt(4) bar
//   ph5-8: same with buf0<->buf1, stages T+2.A->buf0, T+3.B->buf1, vmcnt(4)
// Every stage target is dead (its last reader finished >=1 barrier earlier);
// vmcnt(4) = 2 half-tiles legitimately in flight at each wait point.
// ===========================================================================

#define MFMAQ(AF, BF, mq, nq)                                                  \
  _Pragma("unroll") for (int mi = 0; mi < 4; mi++)                             \
  _Pragma("unroll") for (int ni = 0; ni < 2; ni++)                             \
  _Pragma("unroll") for (int kc = 0; kc < 2; kc++)                             \
    acc[(mq) * 4 + mi][(nq) * 2 + ni] =                                        \
        __builtin_amdgcn_mfma_f32_16x16x32_bf16(                               \
            AF[mi][kc], BF[ni][kc], acc[(mq) * 4 + mi][(nq) * 2 + ni], 0, 0, 0);

#define GROUP(AVc, BVc, stA, stB, ktc)                                         \
  {                                                                            \
    int kA = (ktc) + 64;  if (kA >= K) kA -= K;                                \
    int kB = (ktc) + 128; if (kB >= K) kB -= K;                                \
    const ushort_t* gA = pa + kA;                                              \
    const ushort_t* gB = pb + kB;                                              \
    /* ---- phase 1 ---- */                                                    \
    _Pragma("unroll") for (int mi = 0; mi < 4; mi++)                           \
      _Pragma("unroll") for (int kc = 0; kc < 2; kc++)                         \
        af[mi][kc] = (AVc)[aBase + (mi * 16) * 8 + ck[kc]];                    \
    _Pragma("unroll") for (int ni = 0; ni < 2; ni++)                           \
      _Pragma("unroll") for (int kc = 0; kc < 2; kc++)                         \
        bq0[ni][kc] = (BVc)[bBase + (ni * 16) * 8 + ck[kc]];                   \
    async16(gA,       (stA));                                                  \
    async16(gA + R64, (stA) + 8192);                                           \
    BARRIER(); WAITLGKM0();                                                    \
    __builtin_amdgcn_s_setprio(1);                                             \
    MFMAQ(af, bq0, 0, 0);                                                      \
    __builtin_amdgcn_s_setprio(0);                                             \
    BARRIER();                                                                 \
    /* ---- phase 2 ---- */                                                    \
    _Pragma("unroll") for (int ni = 0; ni < 2; ni++)                           \
      _Pragma("unroll") for (int kc = 0; kc < 2; kc++)                         \
        bq1[ni][kc] = (BVc)[bBase + (32 + ni * 16) * 8 + ck[kc]];              \
    async16(gA + R128,       (stA) + 16384);                                   \
    async16(gA + R128 + R64, (stA) + 16384 + 8192);                            \
    BARRIER(); WAITLGKM0();                                                    \
    __builtin_amdgcn_s_setprio(1);                                             \
    MFMAQ(af, bq1, 0, 1);                                                      \
    __builtin_amdgcn_s_setprio(0);                                             \
    BARRIER();                                                                 \
    /* ---- phase 3 ---- */                                                    \
    _Pragma("unroll") for (int mi = 0; mi < 4; mi++)                           \
      _Pragma("unroll") for (int kc = 0; kc < 2; kc++)                         \
        af[mi][kc] = (AVc)[aBase + (64 + mi * 16) * 8 + ck[kc]];               \
    async16(gB,       (stB));                                                  \
    async16(gB + R64, (stB) + 8192);                                           \
    BARRIER(); WAITLGKM0();                                                    \
    __builtin_amdgcn_s_setprio(1);                                             \
    MFMAQ(af, bq1, 1, 1);                                                      \
    __builtin_amdgcn_s_setprio(0);                                             \
    BARRIER();                                                                 \
    /* ---- phase 4 ---- */                                                    \
    async16(gB + R128,       (stB) + 16384);                                   \
    async16(gB + R128 + R64, (stB) + 16384 + 8192);                            \
    BARRIER();                                                                 \
    __builtin_amdgcn_s_setprio(1);                                             \
    MFMAQ(af, bq0, 1, 0);                                                      \
    __builtin_amdgcn_s_setprio(0);                                             \
    WAITVM4();                                                                 \
    BARRIER();                                                                 \
  }

__global__ __launch_bounds__(512, 2) void gemm256_fc1(
    const ushort_t* __restrict__ A, const ushort_t* __restrict__ Bt,
    const float* __restrict__ bias, ushort_t* __restrict__ outH,
    int M, int N, int K, int ldc)
{
    __shared__ __align__(16) ushort_t As[2][256 * 64];  // 2 x 32 KB
    __shared__ __align__(16) ushort_t Bs[2][256 * 64];  // 2 x 32 KB

    const int tid  = threadIdx.x;
    const int lane = tid & 63;
    const int w    = tid >> 6;
    const int wm   = w >> 2, wn = w & 3;       // 2 x 4 wave grid
    const int m0 = blockIdx.y * 256, n0 = blockIdx.x * 256;

    const int l15 = lane & 15, l4 = lane >> 4, l7 = lane & 7;

    // ---- staging addressing (pre-swizzled global source, linear LDS dest) ----
    const int srow   = tid >> 3;                       // 0..63
    const int schunk = (tid & 7) ^ (srow & 7);         // source 16B chunk
    const size_t R64  = (size_t)64 * K;
    const size_t R128 = (size_t)128 * K;
    const ushort_t* pa = A  + (size_t)(m0 + srow) * K + schunk * 8;
    const ushort_t* pb = Bt + (size_t)(n0 + srow) * K + schunk * 8;
    char* const stA0 = (char*)&As[0][0] + tid * 16;
    char* const stA1 = (char*)&As[1][0] + tid * 16;
    char* const stB0 = (char*)&Bs[0][0] + tid * 16;
    char* const stB1 = (char*)&Bs[1][0] + tid * 16;

    // ---- fragment read addressing (swizzled) ----
    const bf16x8* Av0 = (const bf16x8*)&As[0][0];
    const bf16x8* Av1 = (const bf16x8*)&As[1][0];
    const bf16x8* Bv0 = (const bf16x8*)&Bs[0][0];
    const bf16x8* Bv1 = (const bf16x8*)&Bs[1][0];
    const int aBase = (wm * 128 + l15) * 8;
    const int bBase = (wn * 64 + l15) * 8;
    const int ck[2] = { l4 ^ l7, (4 + l4) ^ l7 };

    f32x4 acc[8][4];
#pragma unroll
    for (int i = 0; i < 8; i++)
#pragma unroll
        for (int j = 0; j < 4; j++) acc[i][j] = (f32x4){0.f, 0.f, 0.f, 0.f};

    bf16x8 af[4][2], bq0[2][2], bq1[2][2];

    // ---- prologue: T0 (k=0) full -> buf0; T1.B (k=64) -> buf1 ----
    async16(pa,              stA0);
    async16(pa + R64,        stA0 + 8192);
    async16(pa + R128,       stA0 + 16384);
    async16(pa + R128 + R64, stA0 + 16384 + 8192);
    async16(pb,              stB0);
    async16(pb + R64,        stB0 + 8192);
    async16(pb + R128,       stB0 + 16384);
    async16(pb + R128 + R64, stB0 + 16384 + 8192);
    async16(pb + 64,              stB1);
    async16(pb + 64 + R64,        stB1 + 8192);
    async16(pb + 64 + R128,       stB1 + 16384);
    async16(pb + 64 + R128 + R64, stB1 + 16384 + 8192);
    WAITVM4();   // T0 fully landed; T1.B (4 loads) still in flight
    BARRIER();

    // ---- main loop: 2 K-tiles per iteration ----
    for (int kt = 0; kt < K; kt += 128) {
        GROUP(Av0, Bv0, stA1, stB0, kt);        // phases 1-4 (even tile)
        GROUP(Av1, Bv1, stA0, stB1, kt + 64);   // phases 5-8 (odd tile)
    }

    // ---- epilogue: relu(acc + bias) -> bf16 ----
    const int colq = l15, rowq = l4 * 4;
#pragma unroll
    for (int nq = 0; nq < 2; nq++)
#pragma unroll
    for (int ni = 0; ni < 2; ni++) {
        int col = n0 + wn * 64 + nq * 32 + ni * 16 + colq;
        float bv = bias[col];
#pragma unroll
        for (int mq = 0; mq < 2; mq++)
#pragma unroll
        for (int mi = 0; mi < 4; mi++) {
            int rowb = m0 + wm * 128 + mq * 64 + mi * 16 + rowq;
#pragma unroll
            for (int r = 0; r < 4; r++) {
                float v = acc[mq * 4 + mi][nq * 2 + ni][r] + bv;
                v = v > 0.f ? v : 0.f;
                outH[(size_t)(rowb + r) * ldc + col] = f2bf(v);
            }
        }
    }
}

// ---------------------------------------------------------------------------
// GEMM C[M,N] = A[M,K] @ Bt[N,K]^T   (A, Bt bf16 row-major; fp32 accumulate)
// Block: 256 thr (4 waves), tile 128x128, BK=32, wave does 64x64 via 4x4 MFMAs.
// FC2: out = C + bias stored fp32, row stride ldc  (kept for FC2 this round)
// ---------------------------------------------------------------------------
template <bool FC1>
__global__ __launch_bounds__(256) void gemm_bt(
    const ushort_t* __restrict__ A, const ushort_t* __restrict__ Bt,
    const float* __restrict__ bias, ushort_t* __restrict__ outH,
    float* __restrict__ outF, int M, int N, int K, int ldc)
{
    __shared__ __align__(16) ushort_t As[128 * 32];  // 8 KB
    __shared__ __align__(16) ushort_t Bs[128 * 32];  // 8 KB

    const int tid  = threadIdx.x;
    const int w    = tid >> 6;
    const int lane = tid & 63;
    const int wm   = w >> 1, wn = w & 1;
    const int m0 = blockIdx.y * 128, n0 = blockIdx.x * 128;

    const int o1 = w * 2048 + lane * 16;
    const int o2 = o1 + 1024;
    const int r1 = o1 >> 6;
    const int kk = (o1 & 63) >> 1;

    const ushort_t* pa = A  + (size_t)(m0 + r1) * K + kk;
    const ushort_t* pb = Bt + (size_t)(n0 + r1) * K + kk;
    const size_t rowstep = (size_t)16 * K;

    char* ldsA1 = (char*)As + o1; char* ldsA2 = (char*)As + o2;
    char* ldsB1 = (char*)Bs + o1; char* ldsB2 = (char*)Bs + o2;

    f32x4 acc[4][4];
#pragma unroll
    for (int i = 0; i < 4; i++)
#pragma unroll
        for (int j = 0; j < 4; j++) acc[i][j] = (f32x4){0.f, 0.f, 0.f, 0.f};

    const bf16x8* Asv = (const bf16x8*)As;
    const bf16x8* Bsv = (const bf16x8*)Bs;
    const int ar = (wm * 64 + (lane & 15)) * 4 + (lane >> 4);
    const int br = (wn * 64 + (lane & 15)) * 4 + (lane >> 4);

    for (int kt = 0; kt < K; kt += 32) {
        async16(pa, ldsA1);
        async16(pa + rowstep, ldsA2);
        async16(pb, ldsB1);
        async16(pb + rowstep, ldsB2);
        pa += 32; pb += 32;
        __syncthreads();

        bf16x8 af[4], bg_[4];
#pragma unroll
        for (int i = 0; i < 4; i++) af[i] = Asv[ar + i * 64];
#pragma unroll
        for (int j = 0; j < 4; j++) bg_[j] = Bsv[br + j * 64];
#pragma unroll
        for (int i = 0; i < 4; i++)
#pragma unroll
            for (int j = 0; j < 4; j++)
                acc[i][j] = __builtin_amdgcn_mfma_f32_16x16x32_bf16(
                    af[i], bg_[j], acc[i][j], 0, 0, 0);
        __syncthreads();
    }

    const int colq = lane & 15, rowq = (lane >> 4) * 4;
#pragma unroll
    for (int j = 0; j < 4; j++) {
        int col = n0 + wn * 64 + j * 16 + colq;
        float bv = bias[col];
#pragma unroll
        for (int i = 0; i < 4; i++) {
            int rowb = m0 + wm * 64 + i * 16 + rowq;
#pragma unroll
            for (int r = 0; r < 4; r++) {
                float v = acc[i][j][r] + bv;
                if (FC1) {
                    v = v > 0.f ? v : 0.f;
                    outH[(size_t)(rowb + r) * ldc + col] = f2bf(v);
                } else {
                    outF[(size_t)(rowb + r) * ldc + col] = v;
                }
            }
        }
    }
}

// ---------------------------------------------------------------------------
// 32x32 tiled transpose + fp32->bf16: in [R,C] -> out [C,R]
// ---------------------------------------------------------------------------
__global__ __launch_bounds__(256) void transpose_cvt(
    const float* __restrict__ in, ushort_t* __restrict__ out, int R, int C)
{
    __shared__ float t[32][33];
    int c0 = blockIdx.x * 32, r0 = blockIdx.y * 32;
    int tx = threadIdx.x, ty = threadIdx.y;
#pragma unroll
    for (int i = 0; i < 4; i++)
        t[ty + i * 8][tx] = in[(size_t)(r0 + ty + i * 8) * C + c0 + tx];
    __syncthreads();
#pragma unroll
    for (int i = 0; i < 4; i++)
        out[(size_t)(c0 + ty + i * 8) * R + r0 + tx] = f2bf(t[tx][ty + i * 8]);
}

// fp32 -> bf16 elementwise, 4 elems/thread
__global__ __launch_bounds__(256) void cvt_bf16x4(
    const float* __restrict__ in, ushort_t* __restrict__ out)
{
    int i = blockIdx.x * 256 + threadIdx.x;
    float4 v = ((const float4*)in)[i];
    unsigned lo = (unsigned)f2bf(v.x) | ((unsigned)f2bf(v.y) << 16);
    unsigned hi = (unsigned)f2bf(v.z) | ((unsigned)f2bf(v.w) << 16);
    ((uint2*)out)[i] = make_uint2(lo, hi);
}

// ---------------------------------------------------------------------------
// Gating: one wave per token. 8 dot products over D=1024, butterfly reduce,
// softmax over E=8. All in fp32 (exact vs ref).
// ---------------------------------------------------------------------------
__global__ __launch_bounds__(256) void gating_kernel(
    const float* __restrict__ x, const float* __restrict__ Wg,
    const float* __restrict__ bg, float* __restrict__ gw)
{
    int lane = threadIdx.x & 63;
    int b = blockIdx.x * 4 + (threadIdx.x >> 6);
    const float* xr = x + (size_t)b * D_DIM;
    float acc[8] = {0, 0, 0, 0, 0, 0, 0, 0};
    for (int k = 0; k < D_DIM / 64; k++) {
        int d = k * 64 + lane;
        float xv = xr[d];
        const float4* wr = (const float4*)(Wg + (size_t)d * 8);
        float4 w0 = wr[0], w1 = wr[1];
        acc[0] += xv * w0.x; acc[1] += xv * w0.y;
        acc[2] += xv * w0.z; acc[3] += xv * w0.w;
        acc[4] += xv * w1.x; acc[5] += xv * w1.y;
        acc[6] += xv * w1.z; acc[7] += xv * w1.w;
    }
#pragma unroll
    for (int off = 32; off > 0; off >>= 1)
#pragma unroll
        for (int e = 0; e < 8; e++) acc[e] += __shfl_xor(acc[e], off, 64);

    float mx = -1e30f;
#pragma unroll
    for (int e = 0; e < 8; e++) { acc[e] += bg[e]; mx = fmaxf(mx, acc[e]); }
    float s = 0.f;
#pragma unroll
    for (int e = 0; e < 8; e++) { acc[e] = expf(acc[e] - mx); s += acc[e]; }
    float outv = acc[0];
#pragma unroll
    for (int e = 1; e < 8; e++) outv = (lane == e) ? acc[e] : outv;
    if (lane < 8) gw[(size_t)b * 8 + lane] = outv / s;
}

// ---------------------------------------------------------------------------
// Mixture: one block per token; thread t handles 4 cols (float4).
// ---------------------------------------------------------------------------
__global__ __launch_bounds__(256) void mixture_kernel(
    const float* __restrict__ gw, const float* __restrict__ eo,
    float* __restrict__ mix)
{
    int b = blockIdx.x, t = threadIdx.x;
    float g[8];
#pragma unroll
    for (int e = 0; e < 8; e++) g[e] = gw[(size_t)b * 8 + e];
    const float4* ep = (const float4*)(eo + (size_t)b * (E_NUM * C_DIM));
    float4 a = make_float4(0.f, 0.f, 0.f, 0.f);
#pragma unroll
    for (int e = 0; e < 8; e++) {
        float4 v = ep[e * 256 + t];
        a.x += g[e] * v.x; a.y += g[e] * v.y;
        a.z += g[e] * v.z; a.w += g[e] * v.w;
    }
    ((float4*)(mix + (size_t)b * C_DIM))[t] = a;
}

// ---------------------------------------------------------------------------
extern "C" void kernel_launch(void* const* d_in, const int* in_sizes, int n_in,
                              void* d_out, int out_size, void* d_ws,
                              size_t ws_size, hipStream_t stream)
{
    const float* x  = (const float*)d_in[0];
    const float* W1 = (const float*)d_in[1];
    const float* b1 = (const float*)d_in[2];
    const float* W2 = (const float*)d_in[3];
    const float* b2 = (const float*)d_in[4];
    const float* Wg = (const float*)d_in[5];
    const float* bg = (const float*)d_in[6];

    // outputs, concatenated flat in return order
    float* mix = (float*)d_out;                        // [B, C]
    float* gw  = mix + (size_t)B_TOK * C_DIM;          // [B, E]
    float* eo  = gw + (size_t)B_TOK * E_NUM;           // [B, E, C]

    // workspace (~96 MB): x_bf16 | W1t_e | W2t_e | h_bf16
    ushort_t* xb  = (ushort_t*)d_ws;                    // B*D
    ushort_t* w1t = xb + (size_t)B_TOK * D_DIM;         // H*D (one expert)
    ushort_t* w2t = w1t + (size_t)H_DIM * D_DIM;        // C*H (one expert)
    ushort_t* hb  = w2t + (size_t)C_DIM * H_DIM;        // B*H

    cvt_bf16x4<<<(B_TOK * D_DIM) / 1024, 256, 0, stream>>>(x, xb);
    gating_kernel<<<B_TOK / 4, 256, 0, stream>>>(x, Wg, bg, gw);

    for (int e = 0; e < E_NUM; e++) {
        // W1[e]: [D,H] -> [H,D] bf16
        transpose_cvt<<<dim3(H_DIM / 32, D_DIM / 32), dim3(32, 8), 0, stream>>>(
            W1 + (size_t)e * D_DIM * H_DIM, w1t, D_DIM, H_DIM);
        // h = relu(x @ W1[e] + b1[e])  [B,H] bf16  -- 256x256 8-phase kernel
        gemm256_fc1<<<dim3(H_DIM / 256, B_TOK / 256), 512, 0, stream>>>(
            xb, w1t, b1 + (size_t)e * H_DIM, hb, B_TOK, H_DIM, D_DIM, H_DIM);
        // W2[e]: [H,C] -> [C,H] bf16
        transpose_cvt<<<dim3(C_DIM / 32, H_DIM / 32), dim3(32, 8), 0, stream>>>(
            W2 + (size_t)e * H_DIM * C_DIM, w2t, H_DIM, C_DIM);
        // eo[:,e,:] = h @ W2[e] + b2[e]  fp32, row stride E*C
        gemm_bt<false><<<dim3(C_DIM / 128, B_TOK / 128), 256, 0, stream>>>(
            hb, w2t, b2 + (size_t)e * C_DIM, nullptr, eo + (size_t)e * C_DIM,
            B_TOK, C_DIM, H_DIM, E_NUM * C_DIM);
    }

    mixture_kernel<<<B_TOK, 256, 0, stream>>>(gw, eo, mix);
}

// Round 2
// 1792.914 us; speedup vs baseline: 1.1966x; 1.1633x over previous
//
#include <hip/hip_runtime.h>

// Problem constants
#define B_TOK 8192
#define D_DIM 1024
#define H_DIM 4096
#define E_NUM 8
#define C_DIM 1024

typedef unsigned short ushort_t;
typedef __attribute__((ext_vector_type(8))) short bf16x8;   // 8 bf16 = 4 VGPRs
typedef __attribute__((ext_vector_type(4))) float f32x4;    // MFMA acc

// round-to-nearest-even fp32 -> bf16
__device__ inline ushort_t f2bf(float f) {
    unsigned u = __float_as_uint(f);
    unsigned r = (u + 0x7fffu + ((u >> 16) & 1u)) >> 16;
    return (ushort_t)r;
}

// async global->LDS, 16B per lane. HW dest = wave-uniform base + lane*16.
__device__ inline void async16(const ushort_t* g, void* l) {
    __builtin_amdgcn_global_load_lds((__attribute__((address_space(1))) void*)g,
                                     (__attribute__((address_space(3))) void*)l,
                                     16, 0, 0);
}

#define FENCE() asm volatile("" ::: "memory")
#define BARRIER() do { FENCE(); __builtin_amdgcn_s_barrier(); FENCE(); } while (0)
#define WAITLGKM0() asm volatile("s_waitcnt lgkmcnt(0)" ::: "memory")
#define WAITVM8()   asm volatile("s_waitcnt vmcnt(8)" ::: "memory")

// ===========================================================================
// 256x256 8-phase bf16 GEMM, deep pipeline (full K-tile ahead).
// C = A[M,K] @ Bt[N,K]^T + bias; RELU_BF16 ? relu->bf16 : fp32 out.
// 512 thr = 8 waves (2M x 4N); per-wave 128x64; BK=64; LDS 128 KiB dbuf.
// grid.z = expert; per-expert offsets eA/eB/eBias/eOut (elements).
//
// LDS per tile buf: [256 rows][64 bf16], XOR swizzle:
//   phys 16B-chunk = logical chunk ^ (row & 7). Staged via global_load_lds
//   (linear dest) with inverse-swizzled global source; reads apply swizzle.
//
// Group (one K-tile t, 4 phases). Buffer liveness drives stage placement:
//   A-buf(t) dead after ph3 reads; B-buf(t) dead after ph2 reads.
//   ph1: rd A.mq0 + B.nq0            | bar | mfma(0,0) | bar
//   ph2: rd B.nq1                    | bar | mfma(0,1) | bar
//   ph3: rd A.mq1 | stage B(t+2) x4  | bar | mfma(1,1) | bar
//   ph4:          | stage A(t+2) x4  | bar | mfma(1,0) | vmcnt(8) bar
// vmcnt(8) leaves exactly the t+2 loads in flight; t+1 loads (issued in
// group t-1 ph3/ph4) get 4-5 phases (~600-750 cy) to land. Never drains to 0.
// ===========================================================================

#define MFMAQ(AF, BF, mq, nq)                                                  \
  _Pragma("unroll") for (int mi = 0; mi < 4; mi++)                             \
  _Pragma("unroll") for (int ni = 0; ni < 2; ni++)                             \
  _Pragma("unroll") for (int kc = 0; kc < 2; kc++)                             \
    acc[(mq) * 4 + mi][(nq) * 2 + ni] =                                        \
        __builtin_amdgcn_mfma_f32_16x16x32_bf16(                               \
            AF[mi][kc], BF[ni][kc], acc[(mq) * 4 + mi][(nq) * 2 + ni], 0, 0, 0);

#define GROUP(AVc, BVc, stA, stB, ktc)                                         \
  {                                                                            \
    int kN = (ktc) + 128; if (kN >= K) kN -= K;                                \
    const ushort_t* gA = pa + kN;                                              \
    const ushort_t* gB = pb + kN;                                              \
    /* ---- phase 1: read A.mq0 + B.nq0 ---- */                                \
    _Pragma("unroll") for (int mi = 0; mi < 4; mi++)                           \
      _Pragma("unroll") for (int kc = 0; kc < 2; kc++)                         \
        af[mi][kc] = (AVc)[aBase + (mi * 16) * 8 + ck[kc]];                    \
    _Pragma("unroll") for (int ni = 0; ni < 2; ni++)                           \
      _Pragma("unroll") for (int kc = 0; kc < 2; kc++)                         \
        bq0[ni][kc] = (BVc)[bBase + (ni * 16) * 8 + ck[kc]];                   \
    BARRIER(); WAITLGKM0();                                                    \
    __builtin_amdgcn_s_setprio(1);                                             \
    MFMAQ(af, bq0, 0, 0);                                                      \
    __builtin_amdgcn_s_setprio(0);                                             \
    BARRIER();                                                                 \
    /* ---- phase 2: read B.nq1 ---- */                                        \
    _Pragma("unroll") for (int ni = 0; ni < 2; ni++)                           \
      _Pragma("unroll") for (int kc = 0; kc < 2; kc++)                         \
        bq1[ni][kc] = (BVc)[bBase + (32 + ni * 16) * 8 + ck[kc]];              \
    BARRIER(); WAITLGKM0();                                                    \
    __builtin_amdgcn_s_setprio(1);                                             \
    MFMAQ(af, bq1, 0, 1);                                                      \
    __builtin_amdgcn_s_setprio(0);                                             \
    BARRIER();                                                                 \
    /* ---- phase 3: read A.mq1 | stage B(t+2) (B-buf dead after ph2) ---- */  \
    _Pragma("unroll") for (int mi = 0; mi < 4; mi++)                           \
      _Pragma("unroll") for (int kc = 0; kc < 2; kc++)                         \
        af[mi][kc] = (AVc)[aBase + (64 + mi * 16) * 8 + ck[kc]];               \
    async16(gB,              (stB));                                           \
    async16(gB + R64,        (stB) + 8192);                                    \
    async16(gB + R128,       (stB) + 16384);                                   \
    async16(gB + R128 + R64, (stB) + 24576);                                   \
    BARRIER(); WAITLGKM0();                                                    \
    __builtin_amdgcn_s_setprio(1);                                             \
    MFMAQ(af, bq1, 1, 1);                                                      \
    __builtin_amdgcn_s_setprio(0);                                             \
    BARRIER();                                                                 \
    /* ---- phase 4: stage A(t+2) (A-buf dead after ph3) ---- */               \
    async16(gA,              (stA));                                           \
    async16(gA + R64,        (stA) + 8192);                                    \
    async16(gA + R128,       (stA) + 16384);                                   \
    async16(gA + R128 + R64, (stA) + 24576);                                   \
    BARRIER();                                                                 \
    __builtin_amdgcn_s_setprio(1);                                             \
    MFMAQ(af, bq0, 1, 0);                                                      \
    __builtin_amdgcn_s_setprio(0);                                             \
    WAITVM8();                                                                 \
    BARRIER();                                                                 \
  }

template <bool RELU_BF16>
__global__ __launch_bounds__(512, 2) void gemm256(
    const ushort_t* __restrict__ A, const ushort_t* __restrict__ Bt,
    const float* __restrict__ bias, ushort_t* __restrict__ outH,
    float* __restrict__ outF, int K, int ldc,
    size_t eA, size_t eB, size_t eBias, size_t eOut)
{
    __shared__ __align__(16) ushort_t As[2][256 * 64];  // 2 x 32 KB
    __shared__ __align__(16) ushort_t Bs[2][256 * 64];  // 2 x 32 KB

    const int z = blockIdx.z;
    A    += (size_t)z * eA;
    Bt   += (size_t)z * eB;
    bias += (size_t)z * eBias;

    const int tid  = threadIdx.x;
    const int lane = tid & 63;
    const int w    = tid >> 6;
    const int wm   = w >> 2, wn = w & 3;       // 2 x 4 wave grid
    const int m0 = blockIdx.y * 256, n0 = blockIdx.x * 256;

    const int l15 = lane & 15, l4 = lane >> 4, l7 = lane & 7;

    // ---- staging addressing (pre-swizzled global source, linear LDS dest) ----
    const int srow   = tid >> 3;                       // 0..63
    const int schunk = (tid & 7) ^ (srow & 7);         // source 16B chunk
    const size_t R64  = (size_t)64 * K;
    const size_t R128 = (size_t)128 * K;
    const ushort_t* pa = A  + (size_t)(m0 + srow) * K + schunk * 8;
    const ushort_t* pb = Bt + (size_t)(n0 + srow) * K + schunk * 8;
    char* const stA0 = (char*)&As[0][0] + tid * 16;
    char* const stA1 = (char*)&As[1][0] + tid * 16;
    char* const stB0 = (char*)&Bs[0][0] + tid * 16;
    char* const stB1 = (char*)&Bs[1][0] + tid * 16;

    // ---- fragment read addressing (swizzled) ----
    const bf16x8* Av0 = (const bf16x8*)&As[0][0];
    const bf16x8* Av1 = (const bf16x8*)&As[1][0];
    const bf16x8* Bv0 = (const bf16x8*)&Bs[0][0];
    const bf16x8* Bv1 = (const bf16x8*)&Bs[1][0];
    const int aBase = (wm * 128 + l15) * 8;
    const int bBase = (wn * 64 + l15) * 8;
    const int ck[2] = { l4 ^ l7, (4 + l4) ^ l7 };

    f32x4 acc[8][4];
#pragma unroll
    for (int i = 0; i < 8; i++)
#pragma unroll
        for (int j = 0; j < 4; j++) acc[i][j] = (f32x4){0.f, 0.f, 0.f, 0.f};

    bf16x8 af[4][2], bq0[2][2], bq1[2][2];

    // ---- prologue: stage tile 0 -> buf0, tile 1 -> buf1 (16 loads) ----
    async16(pa,              stA0);
    async16(pa + R64,        stA0 + 8192);
    async16(pa + R128,       stA0 + 16384);
    async16(pa + R128 + R64, stA0 + 24576);
    async16(pb,              stB0);
    async16(pb + R64,        stB0 + 8192);
    async16(pb + R128,       stB0 + 16384);
    async16(pb + R128 + R64, stB0 + 24576);
    async16(pa + 64,              stA1);
    async16(pa + 64 + R64,        stA1 + 8192);
    async16(pa + 64 + R128,       stA1 + 16384);
    async16(pa + 64 + R128 + R64, stA1 + 24576);
    async16(pb + 64,              stB1);
    async16(pb + 64 + R64,        stB1 + 8192);
    async16(pb + 64 + R128,       stB1 + 16384);
    async16(pb + 64 + R128 + R64, stB1 + 24576);
    WAITVM8();   // tile 0 fully landed; tile 1 (8 loads) still in flight
    BARRIER();

    // ---- main loop: 2 K-tiles per iteration; group t stages tile t+2 ----
    for (int kt = 0; kt < K; kt += 128) {
        GROUP(Av0, Bv0, stA0, stB0, kt);        // tile kt     (buf0)
        GROUP(Av1, Bv1, stA1, stB1, kt + 64);   // tile kt+64  (buf1)
    }

    // ---- epilogue ----
    const int colq = l15, rowq = l4 * 4;
#pragma unroll
    for (int nq = 0; nq < 2; nq++)
#pragma unroll
    for (int ni = 0; ni < 2; ni++) {
        int col = n0 + wn * 64 + nq * 32 + ni * 16 + colq;
        float bv = bias[col];
#pragma unroll
        for (int mq = 0; mq < 2; mq++)
#pragma unroll
        for (int mi = 0; mi < 4; mi++) {
            int rowb = m0 + wm * 128 + mq * 64 + mi * 16 + rowq;
#pragma unroll
            for (int r = 0; r < 4; r++) {
                float v = acc[mq * 4 + mi][nq * 2 + ni][r] + bv;
                if (RELU_BF16) {
                    v = v > 0.f ? v : 0.f;
                    (outH + (size_t)z * eOut)[(size_t)(rowb + r) * ldc + col] = f2bf(v);
                } else {
                    (outF + (size_t)z * eOut)[(size_t)(rowb + r) * ldc + col] = v;
                }
            }
        }
    }
}

// ---------------------------------------------------------------------------
// Fallback FC2 GEMM (m97-structure 128x128), used only if workspace is small.
// ---------------------------------------------------------------------------
__global__ __launch_bounds__(256) void gemm_bt_f32(
    const ushort_t* __restrict__ A, const ushort_t* __restrict__ Bt,
    const float* __restrict__ bias, float* __restrict__ outF,
    int M, int N, int K, int ldc)
{
    __shared__ __align__(16) ushort_t As[128 * 32];
    __shared__ __align__(16) ushort_t Bs[128 * 32];

    const int tid  = threadIdx.x;
    const int w    = tid >> 6;
    const int lane = tid & 63;
    const int wm   = w >> 1, wn = w & 1;
    const int m0 = blockIdx.y * 128, n0 = blockIdx.x * 128;

    const int o1 = w * 2048 + lane * 16;
    const int o2 = o1 + 1024;
    const int r1 = o1 >> 6;
    const int kk = (o1 & 63) >> 1;

    const ushort_t* pa = A  + (size_t)(m0 + r1) * K + kk;
    const ushort_t* pb = Bt + (size_t)(n0 + r1) * K + kk;
    const size_t rowstep = (size_t)16 * K;

    char* ldsA1 = (char*)As + o1; char* ldsA2 = (char*)As + o2;
    char* ldsB1 = (char*)Bs + o1; char* ldsB2 = (char*)Bs + o2;

    f32x4 acc[4][4];
#pragma unroll
    for (int i = 0; i < 4; i++)
#pragma unroll
        for (int j = 0; j < 4; j++) acc[i][j] = (f32x4){0.f, 0.f, 0.f, 0.f};

    const bf16x8* Asv = (const bf16x8*)As;
    const bf16x8* Bsv = (const bf16x8*)Bs;
    const int ar = (wm * 64 + (lane & 15)) * 4 + (lane >> 4);
    const int br = (wn * 64 + (lane & 15)) * 4 + (lane >> 4);

    for (int kt = 0; kt < K; kt += 32) {
        async16(pa, ldsA1);
        async16(pa + rowstep, ldsA2);
        async16(pb, ldsB1);
        async16(pb + rowstep, ldsB2);
        pa += 32; pb += 32;
        __syncthreads();

        bf16x8 af[4], bg_[4];
#pragma unroll
        for (int i = 0; i < 4; i++) af[i] = Asv[ar + i * 64];
#pragma unroll
        for (int j = 0; j < 4; j++) bg_[j] = Bsv[br + j * 64];
#pragma unroll
        for (int i = 0; i < 4; i++)
#pragma unroll
            for (int j = 0; j < 4; j++)
                acc[i][j] = __builtin_amdgcn_mfma_f32_16x16x32_bf16(
                    af[i], bg_[j], acc[i][j], 0, 0, 0);
        __syncthreads();
    }

    const int colq = lane & 15, rowq = (lane >> 4) * 4;
#pragma unroll
    for (int j = 0; j < 4; j++) {
        int col = n0 + wn * 64 + j * 16 + colq;
        float bv = bias[col];
#pragma unroll
        for (int i = 0; i < 4; i++) {
            int rowb = m0 + wm * 64 + i * 16 + rowq;
#pragma unroll
            for (int r = 0; r < 4; r++)
                outF[(size_t)(rowb + r) * ldc + col] = acc[i][j][r] + bv;
        }
    }
}

// ---------------------------------------------------------------------------
// 32x32 tiled transpose + fp32->bf16: in [R,C] -> out [C,R]; grid.z batches.
// ---------------------------------------------------------------------------
__global__ __launch_bounds__(256) void transpose_cvt(
    const float* __restrict__ in, ushort_t* __restrict__ out, int R, int C)
{
    __shared__ float t[32][33];
    size_t zoff = (size_t)blockIdx.z * R * C;
    in  += zoff;
    out += zoff;
    int c0 = blockIdx.x * 32, r0 = blockIdx.y * 32;
    int tx = threadIdx.x, ty = threadIdx.y;
#pragma unroll
    for (int i = 0; i < 4; i++)
        t[ty + i * 8][tx] = in[(size_t)(r0 + ty + i * 8) * C + c0 + tx];
    __syncthreads();
#pragma unroll
    for (int i = 0; i < 4; i++)
        out[(size_t)(c0 + ty + i * 8) * R + r0 + tx] = f2bf(t[tx][ty + i * 8]);
}

// fp32 -> bf16 elementwise, 4 elems/thread
__global__ __launch_bounds__(256) void cvt_bf16x4(
    const float* __restrict__ in, ushort_t* __restrict__ out)
{
    int i = blockIdx.x * 256 + threadIdx.x;
    float4 v = ((const float4*)in)[i];
    unsigned lo = (unsigned)f2bf(v.x) | ((unsigned)f2bf(v.y) << 16);
    unsigned hi = (unsigned)f2bf(v.z) | ((unsigned)f2bf(v.w) << 16);
    ((uint2*)out)[i] = make_uint2(lo, hi);
}

// ---------------------------------------------------------------------------
// Gating: one wave per token. 8 dot products over D=1024, butterfly reduce,
// softmax over E=8. All in fp32 (exact vs ref).
// ---------------------------------------------------------------------------
__global__ __launch_bounds__(256) void gating_kernel(
    const float* __restrict__ x, const float* __restrict__ Wg,
    const float* __restrict__ bg, float* __restrict__ gw)
{
    int lane = threadIdx.x & 63;
    int b = blockIdx.x * 4 + (threadIdx.x >> 6);
    const float* xr = x + (size_t)b * D_DIM;
    float acc[8] = {0, 0, 0, 0, 0, 0, 0, 0};
    for (int k = 0; k < D_DIM / 64; k++) {
        int d = k * 64 + lane;
        float xv = xr[d];
        const float4* wr = (const float4*)(Wg + (size_t)d * 8);
        float4 w0 = wr[0], w1 = wr[1];
        acc[0] += xv * w0.x; acc[1] += xv * w0.y;
        acc[2] += xv * w0.z; acc[3] += xv * w0.w;
        acc[4] += xv * w1.x; acc[5] += xv * w1.y;
        acc[6] += xv * w1.z; acc[7] += xv * w1.w;
    }
#pragma unroll
    for (int off = 32; off > 0; off >>= 1)
#pragma unroll
        for (int e = 0; e < 8; e++) acc[e] += __shfl_xor(acc[e], off, 64);

    float mx = -1e30f;
#pragma unroll
    for (int e = 0; e < 8; e++) { acc[e] += bg[e]; mx = fmaxf(mx, acc[e]); }
    float s = 0.f;
#pragma unroll
    for (int e = 0; e < 8; e++) { acc[e] = expf(acc[e] - mx); s += acc[e]; }
    float outv = acc[0];
#pragma unroll
    for (int e = 1; e < 8; e++) outv = (lane == e) ? acc[e] : outv;
    if (lane < 8) gw[(size_t)b * 8 + lane] = outv / s;
}

// ---------------------------------------------------------------------------
// Mixture: one block per token; thread t handles 4 cols (float4).
// ---------------------------------------------------------------------------
__global__ __launch_bounds__(256) void mixture_kernel(
    const float* __restrict__ gw, const float* __restrict__ eo,
    float* __restrict__ mix)
{
    int b = blockIdx.x, t = threadIdx.x;
    float g[8];
#pragma unroll
    for (int e = 0; e < 8; e++) g[e] = gw[(size_t)b * 8 + e];
    const float4* ep = (const float4*)(eo + (size_t)b * (E_NUM * C_DIM));
    float4 a = make_float4(0.f, 0.f, 0.f, 0.f);
#pragma unroll
    for (int e = 0; e < 8; e++) {
        float4 v = ep[e * 256 + t];
        a.x += g[e] * v.x; a.y += g[e] * v.y;
        a.z += g[e] * v.z; a.w += g[e] * v.w;
    }
    ((float4*)(mix + (size_t)b * C_DIM))[t] = a;
}

// ---------------------------------------------------------------------------
extern "C" void kernel_launch(void* const* d_in, const int* in_sizes, int n_in,
                              void* d_out, int out_size, void* d_ws,
                              size_t ws_size, hipStream_t stream)
{
    const float* x  = (const float*)d_in[0];
    const float* W1 = (const float*)d_in[1];
    const float* b1 = (const float*)d_in[2];
    const float* W2 = (const float*)d_in[3];
    const float* b2 = (const float*)d_in[4];
    const float* Wg = (const float*)d_in[5];
    const float* bg = (const float*)d_in[6];

    // outputs, concatenated flat in return order
    float* mix = (float*)d_out;                        // [B, C]
    float* gw  = mix + (size_t)B_TOK * C_DIM;          // [B, E]
    float* eo  = gw + (size_t)B_TOK * E_NUM;           // [B, E, C]

    const size_t nXB  = (size_t)B_TOK * D_DIM;          // x bf16
    const size_t nW1e = (size_t)H_DIM * D_DIM;          // one expert W1^T
    const size_t nW2e = (size_t)C_DIM * H_DIM;          // one expert W2^T
    const size_t nHBe = (size_t)B_TOK * H_DIM;          // one expert h

    const size_t needBig = (nXB + 8 * nW1e + 8 * nW2e + 8 * nHBe) * sizeof(ushort_t);

    cvt_bf16x4<<<(B_TOK * D_DIM) / 1024, 256, 0, stream>>>(x, (ushort_t*)d_ws);
    gating_kernel<<<B_TOK / 4, 256, 0, stream>>>(x, Wg, bg, gw);

    if (ws_size >= needBig) {
        // ---- mega path: batch everything over experts, 7 dispatches ----
        ushort_t* xb     = (ushort_t*)d_ws;             // B*D
        ushort_t* w1tAll = xb + nXB;                    // 8*H*D
        ushort_t* w2tAll = w1tAll + 8 * nW1e;           // 8*C*H
        ushort_t* hbAll  = w2tAll + 8 * nW2e;           // 8*B*H

        transpose_cvt<<<dim3(H_DIM / 32, D_DIM / 32, 8), dim3(32, 8), 0, stream>>>(
            W1, w1tAll, D_DIM, H_DIM);
        transpose_cvt<<<dim3(C_DIM / 32, H_DIM / 32, 8), dim3(32, 8), 0, stream>>>(
            W2, w2tAll, H_DIM, C_DIM);

        // FC1 mega: h[e] = relu(x @ W1[e] + b1[e]),  grid 16x32x8
        gemm256<true><<<dim3(H_DIM / 256, B_TOK / 256, 8), 512, 0, stream>>>(
            xb, w1tAll, b1, hbAll, nullptr, D_DIM, H_DIM,
            0, nW1e, H_DIM, nHBe);

        // FC2 mega: eo[:,e,:] = h[e] @ W2[e] + b2[e],  grid 4x32x8 (m201 shape)
        gemm256<false><<<dim3(C_DIM / 256, B_TOK / 256, 8), 512, 0, stream>>>(
            hbAll, w2tAll, b2, nullptr, eo, H_DIM, E_NUM * C_DIM,
            nHBe, nW2e, C_DIM, C_DIM);
    } else {
        // ---- fallback: per-expert loop (small workspace) ----
        ushort_t* xb  = (ushort_t*)d_ws;
        ushort_t* w1t = xb + nXB;
        ushort_t* w2t = w1t + nW1e;
        ushort_t* hb  = w2t + nW2e;

        for (int e = 0; e < E_NUM; e++) {
            transpose_cvt<<<dim3(H_DIM / 32, D_DIM / 32, 1), dim3(32, 8), 0, stream>>>(
                W1 + (size_t)e * D_DIM * H_DIM, w1t, D_DIM, H_DIM);
            gemm256<true><<<dim3(H_DIM / 256, B_TOK / 256, 1), 512, 0, stream>>>(
                xb, w1t, b1 + (size_t)e * H_DIM, hb, nullptr, D_DIM, H_DIM,
                0, 0, 0, 0);
            transpose_cvt<<<dim3(C_DIM / 32, H_DIM / 32, 1), dim3(32, 8), 0, stream>>>(
                W2 + (size_t)e * H_DIM * C_DIM, w2t, H_DIM, C_DIM);
            gemm_bt_f32<<<dim3(C_DIM / 128, B_TOK / 128), 256, 0, stream>>>(
                hb, w2t, b2 + (size_t)e * C_DIM, eo + (size_t)e * C_DIM,
                B_TOK, C_DIM, H_DIM, E_NUM * C_DIM);
        }
    }

    mixture_kernel<<<B_TOK, 256, 0, stream>>>(gw, eo, mix);
}

// Round 3
// 1771.002 us; speedup vs baseline: 1.2115x; 1.0124x over previous
//
#include <hip/hip_runtime.h>

// Problem constants
#define B_TOK 8192
#define D_DIM 1024
#define H_DIM 4096
#define E_NUM 8
#define C_DIM 1024

typedef unsigned short ushort_t;
typedef __attribute__((ext_vector_type(8))) short bf16x8;   // 8 bf16 = 4 VGPRs
typedef __attribute__((ext_vector_type(4))) float f32x4;    // MFMA acc

// round-to-nearest-even fp32 -> bf16
__device__ inline ushort_t f2bf(float f) {
    unsigned u = __float_as_uint(f);
    unsigned r = (u + 0x7fffu + ((u >> 16) & 1u)) >> 16;
    return (ushort_t)r;
}

// async global->LDS, 16B per lane. HW dest = wave-uniform base + lane*16.
__device__ inline void async16(const ushort_t* g, void* l) {
    __builtin_amdgcn_global_load_lds((__attribute__((address_space(1))) void*)g,
                                     (__attribute__((address_space(3))) void*)l,
                                     16, 0, 0);
}

#define FENCE() asm volatile("" ::: "memory")
#define BARRIER() do { FENCE(); __builtin_amdgcn_s_barrier(); FENCE(); } while (0)
#define WAITLGKM0() asm volatile("s_waitcnt lgkmcnt(0)" ::: "memory")
#define WAITVM8()   asm volatile("s_waitcnt vmcnt(8)" ::: "memory")

// ===========================================================================
// 256x256 8-phase bf16 GEMM, deep pipeline (full K-tile ahead), XCD-swizzled.
// C = A[M,K] @ Bt[N,K]^T + bias; RELU_BF16 ? relu->bf16 : fp32 out.
// 512 thr = 8 waves (2M x 4N); per-wave 128x64; BK=64; LDS 128 KiB dbuf.
//
// Grid is 1D, nwg % 8 == 0. Block remap (bijective, m204 chunked form):
//   wgid = (bid & 7) * (nwg/8) + (bid >> 3)      // XCD k owns chunk k
//   z    = wgid / perE                            // expert (chunk == expert)
//   r    = wgid % perE
//   g    = r / (supM*nGrid); rem = r % (supM*nGrid);
//   n    = rem / supM;  m = g*supM + rem % supM
// FC1 (perE=512, nGrid=16, supM=4): co-resident 32 blocks/XCD = 4m x 8n
//   -> A 2 MB + B 4 MB working set, L2-resident, panels reused 4-8x hot.
// FC2 (perE=128, nGrid=4, supM=1): 4 consecutive blocks share one h-panel
//   (2 MB, the dominant stream); W2 window (8 MB) recycles at spacing 4.
//
// LDS per tile buf: [256 rows][64 bf16], XOR swizzle:
//   phys 16B-chunk = logical chunk ^ (row & 7). Staged via global_load_lds
//   (linear dest) with inverse-swizzled global source; reads apply swizzle.
//
// Group (one K-tile t, 4 phases). Buffer liveness drives stage placement:
//   A-buf(t) dead after ph3 reads; B-buf(t) dead after ph2 reads.
//   ph1: rd A.mq0 + B.nq0            | bar | mfma(0,0) | bar
//   ph2: rd B.nq1                    | bar | mfma(0,1) | bar
//   ph3: rd A.mq1 | stage B(t+2) x4  | bar | mfma(1,1) | bar
//   ph4:          | stage A(t+2) x4  | bar | mfma(1,0) | vmcnt(8) bar
// vmcnt(8) leaves exactly the t+2 loads in flight; t+1 loads get 4-5 phases
// (~600-750 cy) to land. Never drains to 0 in the main loop.
// ===========================================================================

#define MFMAQ(AF, BF, mq, nq)                                                  \
  _Pragma("unroll") for (int mi = 0; mi < 4; mi++)                             \
  _Pragma("unroll") for (int ni = 0; ni < 2; ni++)                             \
  _Pragma("unroll") for (int kc = 0; kc < 2; kc++)                             \
    acc[(mq) * 4 + mi][(nq) * 2 + ni] =                                        \
        __builtin_amdgcn_mfma_f32_16x16x32_bf16(                               \
            AF[mi][kc], BF[ni][kc], acc[(mq) * 4 + mi][(nq) * 2 + ni], 0, 0, 0);

#define GROUP(AVc, BVc, stA, stB, ktc)                                         \
  {                                                                            \
    int kN = (ktc) + 128; if (kN >= K) kN -= K;                                \
    const ushort_t* gA = pa + kN;                                              \
    const ushort_t* gB = pb + kN;                                              \
    /* ---- phase 1: read A.mq0 + B.nq0 ---- */                                \
    _Pragma("unroll") for (int mi = 0; mi < 4; mi++)                           \
      _Pragma("unroll") for (int kc = 0; kc < 2; kc++)                         \
        af[mi][kc] = (AVc)[aBase + (mi * 16) * 8 + ck[kc]];                    \
    _Pragma("unroll") for (int ni = 0; ni < 2; ni++)                           \
      _Pragma("unroll") for (int kc = 0; kc < 2; kc++)                         \
        bq0[ni][kc] = (BVc)[bBase + (ni * 16) * 8 + ck[kc]];                   \
    BARRIER(); WAITLGKM0();                                                    \
    __builtin_amdgcn_s_setprio(1);                                             \
    MFMAQ(af, bq0, 0, 0);                                                      \
    __builtin_amdgcn_s_setprio(0);                                             \
    BARRIER();                                                                 \
    /* ---- phase 2: read B.nq1 ---- */                                        \
    _Pragma("unroll") for (int ni = 0; ni < 2; ni++)                           \
      _Pragma("unroll") for (int kc = 0; kc < 2; kc++)                         \
        bq1[ni][kc] = (BVc)[bBase + (32 + ni * 16) * 8 + ck[kc]];              \
    BARRIER(); WAITLGKM0();                                                    \
    __builtin_amdgcn_s_setprio(1);                                             \
    MFMAQ(af, bq1, 0, 1);                                                      \
    __builtin_amdgcn_s_setprio(0);                                             \
    BARRIER();                                                                 \
    /* ---- phase 3: read A.mq1 | stage B(t+2) (B-buf dead after ph2) ---- */  \
    _Pragma("unroll") for (int mi = 0; mi < 4; mi++)                           \
      _Pragma("unroll") for (int kc = 0; kc < 2; kc++)                         \
        af[mi][kc] = (AVc)[aBase + (64 + mi * 16) * 8 + ck[kc]];               \
    async16(gB,              (stB));                                           \
    async16(gB + R64,        (stB) + 8192);                                    \
    async16(gB + R128,       (stB) + 16384);                                   \
    async16(gB + R128 + R64, (stB) + 24576);                                   \
    BARRIER(); WAITLGKM0();                                                    \
    __builtin_amdgcn_s_setprio(1);                                             \
    MFMAQ(af, bq1, 1, 1);                                                      \
    __builtin_amdgcn_s_setprio(0);                                             \
    BARRIER();                                                                 \
    /* ---- phase 4: stage A(t+2) (A-buf dead after ph3) ---- */               \
    async16(gA,              (stA));                                           \
    async16(gA + R64,        (stA) + 8192);                                    \
    async16(gA + R128,       (stA) + 16384);                                   \
    async16(gA + R128 + R64, (stA) + 24576);                                   \
    BARRIER();                                                                 \
    __builtin_amdgcn_s_setprio(1);                                             \
    MFMAQ(af, bq0, 1, 0);                                                      \
    __builtin_amdgcn_s_setprio(0);                                             \
    WAITVM8();                                                                 \
    BARRIER();                                                                 \
  }

template <bool RELU_BF16>
__global__ __launch_bounds__(512, 2) void gemm256(
    const ushort_t* __restrict__ A, const ushort_t* __restrict__ Bt,
    const float* __restrict__ bias, ushort_t* __restrict__ outH,
    float* __restrict__ outF, int K, int ldc,
    size_t eA, size_t eB, size_t eBias, size_t eOut,
    int perE, int nGrid, int supM)
{
    __shared__ __align__(16) ushort_t As[2][256 * 64];  // 2 x 32 KB
    __shared__ __align__(16) ushort_t Bs[2][256 * 64];  // 2 x 32 KB

    // ---- XCD-chunked block remap + supertile decode ----
    const int nwg  = (int)gridDim.x;
    const int bid  = (int)blockIdx.x;
    const int wgid = (bid & 7) * (nwg >> 3) + (bid >> 3);
    const int z    = wgid / perE;
    const int r    = wgid - z * perE;
    const int sng  = supM * nGrid;
    const int g    = r / sng;
    const int rem  = r - g * sng;
    const int nb   = rem / supM;
    const int mb   = g * supM + (rem - nb * supM);
    const int m0 = mb * 256, n0 = nb * 256;

    A    += (size_t)z * eA;
    Bt   += (size_t)z * eB;
    bias += (size_t)z * eBias;

    const int tid  = threadIdx.x;
    const int lane = tid & 63;
    const int w    = tid >> 6;
    const int wm   = w >> 2, wn = w & 3;       // 2 x 4 wave grid

    const int l15 = lane & 15, l4 = lane >> 4, l7 = lane & 7;

    // ---- staging addressing (pre-swizzled global source, linear LDS dest) ----
    const int srow   = tid >> 3;                       // 0..63
    const int schunk = (tid & 7) ^ (srow & 7);         // source 16B chunk
    const size_t R64  = (size_t)64 * K;
    const size_t R128 = (size_t)128 * K;
    const ushort_t* pa = A  + (size_t)(m0 + srow) * K + schunk * 8;
    const ushort_t* pb = Bt + (size_t)(n0 + srow) * K + schunk * 8;
    char* const stA0 = (char*)&As[0][0] + tid * 16;
    char* const stA1 = (char*)&As[1][0] + tid * 16;
    char* const stB0 = (char*)&Bs[0][0] + tid * 16;
    char* const stB1 = (char*)&Bs[1][0] + tid * 16;

    // ---- fragment read addressing (swizzled) ----
    const bf16x8* Av0 = (const bf16x8*)&As[0][0];
    const bf16x8* Av1 = (const bf16x8*)&As[1][0];
    const bf16x8* Bv0 = (const bf16x8*)&Bs[0][0];
    const bf16x8* Bv1 = (const bf16x8*)&Bs[1][0];
    const int aBase = (wm * 128 + l15) * 8;
    const int bBase = (wn * 64 + l15) * 8;
    const int ck[2] = { l4 ^ l7, (4 + l4) ^ l7 };

    f32x4 acc[8][4];
#pragma unroll
    for (int i = 0; i < 8; i++)
#pragma unroll
        for (int j = 0; j < 4; j++) acc[i][j] = (f32x4){0.f, 0.f, 0.f, 0.f};

    bf16x8 af[4][2], bq0[2][2], bq1[2][2];

    // ---- prologue: stage tile 0 -> buf0, tile 1 -> buf1 (16 loads) ----
    async16(pa,              stA0);
    async16(pa + R64,        stA0 + 8192);
    async16(pa + R128,       stA0 + 16384);
    async16(pa + R128 + R64, stA0 + 24576);
    async16(pb,              stB0);
    async16(pb + R64,        stB0 + 8192);
    async16(pb + R128,       stB0 + 16384);
    async16(pb + R128 + R64, stB0 + 24576);
    async16(pa + 64,              stA1);
    async16(pa + 64 + R64,        stA1 + 8192);
    async16(pa + 64 + R128,       stA1 + 16384);
    async16(pa + 64 + R128 + R64, stA1 + 24576);
    async16(pb + 64,              stB1);
    async16(pb + 64 + R64,        stB1 + 8192);
    async16(pb + 64 + R128,       stB1 + 16384);
    async16(pb + 64 + R128 + R64, stB1 + 24576);
    WAITVM8();   // tile 0 fully landed; tile 1 (8 loads) still in flight
    BARRIER();

    // ---- main loop: 2 K-tiles per iteration; group t stages tile t+2 ----
    for (int kt = 0; kt < K; kt += 128) {
        GROUP(Av0, Bv0, stA0, stB0, kt);        // tile kt     (buf0)
        GROUP(Av1, Bv1, stA1, stB1, kt + 64);   // tile kt+64  (buf1)
    }

    // ---- epilogue ----
    const int colq = l15, rowq = l4 * 4;
#pragma unroll
    for (int nq = 0; nq < 2; nq++)
#pragma unroll
    for (int ni = 0; ni < 2; ni++) {
        int col = n0 + wn * 64 + nq * 32 + ni * 16 + colq;
        float bv = bias[col];
#pragma unroll
        for (int mq = 0; mq < 2; mq++)
#pragma unroll
        for (int mi = 0; mi < 4; mi++) {
            int rowb = m0 + wm * 128 + mq * 64 + mi * 16 + rowq;
#pragma unroll
            for (int r2 = 0; r2 < 4; r2++) {
                float v = acc[mq * 4 + mi][nq * 2 + ni][r2] + bv;
                if (RELU_BF16) {
                    v = v > 0.f ? v : 0.f;
                    (outH + (size_t)z * eOut)[(size_t)(rowb + r2) * ldc + col] = f2bf(v);
                } else {
                    (outF + (size_t)z * eOut)[(size_t)(rowb + r2) * ldc + col] = v;
                }
            }
        }
    }
}

// ---------------------------------------------------------------------------
// Fallback FC2 GEMM (m97-structure 128x128), used only if workspace is small.
// ---------------------------------------------------------------------------
__global__ __launch_bounds__(256) void gemm_bt_f32(
    const ushort_t* __restrict__ A, const ushort_t* __restrict__ Bt,
    const float* __restrict__ bias, float* __restrict__ outF,
    int M, int N, int K, int ldc)
{
    __shared__ __align__(16) ushort_t As[128 * 32];
    __shared__ __align__(16) ushort_t Bs[128 * 32];

    const int tid  = threadIdx.x;
    const int w    = tid >> 6;
    const int lane = tid & 63;
    const int wm   = w >> 1, wn = w & 1;
    const int m0 = blockIdx.y * 128, n0 = blockIdx.x * 128;

    const int o1 = w * 2048 + lane * 16;
    const int o2 = o1 + 1024;
    const int r1 = o1 >> 6;
    const int kk = (o1 & 63) >> 1;

    const ushort_t* pa = A  + (size_t)(m0 + r1) * K + kk;
    const ushort_t* pb = Bt + (size_t)(n0 + r1) * K + kk;
    const size_t rowstep = (size_t)16 * K;

    char* ldsA1 = (char*)As + o1; char* ldsA2 = (char*)As + o2;
    char* ldsB1 = (char*)Bs + o1; char* ldsB2 = (char*)Bs + o2;

    f32x4 acc[4][4];
#pragma unroll
    for (int i = 0; i < 4; i++)
#pragma unroll
        for (int j = 0; j < 4; j++) acc[i][j] = (f32x4){0.f, 0.f, 0.f, 0.f};

    const bf16x8* Asv = (const bf16x8*)As;
    const bf16x8* Bsv = (const bf16x8*)Bs;
    const int ar = (wm * 64 + (lane & 15)) * 4 + (lane >> 4);
    const int br = (wn * 64 + (lane & 15)) * 4 + (lane >> 4);

    for (int kt = 0; kt < K; kt += 32) {
        async16(pa, ldsA1);
        async16(pa + rowstep, ldsA2);
        async16(pb, ldsB1);
        async16(pb + rowstep, ldsB2);
        pa += 32; pb += 32;
        __syncthreads();

        bf16x8 af[4], bg_[4];
#pragma unroll
        for (int i = 0; i < 4; i++) af[i] = Asv[ar + i * 64];
#pragma unroll
        for (int j = 0; j < 4; j++) bg_[j] = Bsv[br + j * 64];
#pragma unroll
        for (int i = 0; i < 4; i++)
#pragma unroll
            for (int j = 0; j < 4; j++)
                acc[i][j] = __builtin_amdgcn_mfma_f32_16x16x32_bf16(
                    af[i], bg_[j], acc[i][j], 0, 0, 0);
        __syncthreads();
    }

    const int colq = lane & 15, rowq = (lane >> 4) * 4;
#pragma unroll
    for (int j = 0; j < 4; j++) {
        int col = n0 + wn * 64 + j * 16 + colq;
        float bv = bias[col];
#pragma unroll
        for (int i = 0; i < 4; i++) {
            int rowb = m0 + wm * 64 + i * 16 + rowq;
#pragma unroll
            for (int r = 0; r < 4; r++)
                outF[(size_t)(rowb + r) * ldc + col] = acc[i][j][r] + bv;
        }
    }
}

// ---------------------------------------------------------------------------
// 32x32 tiled transpose + fp32->bf16: in [R,C] -> out [C,R]; grid.z batches.
// ---------------------------------------------------------------------------
__global__ __launch_bounds__(256) void transpose_cvt(
    const float* __restrict__ in, ushort_t* __restrict__ out, int R, int C)
{
    __shared__ float t[32][33];
    size_t zoff = (size_t)blockIdx.z * R * C;
    in  += zoff;
    out += zoff;
    int c0 = blockIdx.x * 32, r0 = blockIdx.y * 32;
    int tx = threadIdx.x, ty = threadIdx.y;
#pragma unroll
    for (int i = 0; i < 4; i++)
        t[ty + i * 8][tx] = in[(size_t)(r0 + ty + i * 8) * C + c0 + tx];
    __syncthreads();
#pragma unroll
    for (int i = 0; i < 4; i++)
        out[(size_t)(c0 + ty + i * 8) * R + r0 + tx] = f2bf(t[tx][ty + i * 8]);
}

// fp32 -> bf16 elementwise, 4 elems/thread
__global__ __launch_bounds__(256) void cvt_bf16x4(
    const float* __restrict__ in, ushort_t* __restrict__ out)
{
    int i = blockIdx.x * 256 + threadIdx.x;
    float4 v = ((const float4*)in)[i];
    unsigned lo = (unsigned)f2bf(v.x) | ((unsigned)f2bf(v.y) << 16);
    unsigned hi = (unsigned)f2bf(v.z) | ((unsigned)f2bf(v.w) << 16);
    ((uint2*)out)[i] = make_uint2(lo, hi);
}

// ---------------------------------------------------------------------------
// Gating: one wave per token. 8 dot products over D=1024, butterfly reduce,
// softmax over E=8. All in fp32 (exact vs ref).
// ---------------------------------------------------------------------------
__global__ __launch_bounds__(256) void gating_kernel(
    const float* __restrict__ x, const float* __restrict__ Wg,
    const float* __restrict__ bg, float* __restrict__ gw)
{
    int lane = threadIdx.x & 63;
    int b = blockIdx.x * 4 + (threadIdx.x >> 6);
    const float* xr = x + (size_t)b * D_DIM;
    float acc[8] = {0, 0, 0, 0, 0, 0, 0, 0};
    for (int k = 0; k < D_DIM / 64; k++) {
        int d = k * 64 + lane;
        float xv = xr[d];
        const float4* wr = (const float4*)(Wg + (size_t)d * 8);
        float4 w0 = wr[0], w1 = wr[1];
        acc[0] += xv * w0.x; acc[1] += xv * w0.y;
        acc[2] += xv * w0.z; acc[3] += xv * w0.w;
        acc[4] += xv * w1.x; acc[5] += xv * w1.y;
        acc[6] += xv * w1.z; acc[7] += xv * w1.w;
    }
#pragma unroll
    for (int off = 32; off > 0; off >>= 1)
#pragma unroll
        for (int e = 0; e < 8; e++) acc[e] += __shfl_xor(acc[e], off, 64);

    float mx = -1e30f;
#pragma unroll
    for (int e = 0; e < 8; e++) { acc[e] += bg[e]; mx = fmaxf(mx, acc[e]); }
    float s = 0.f;
#pragma unroll
    for (int e = 0; e < 8; e++) { acc[e] = expf(acc[e] - mx); s += acc[e]; }
    float outv = acc[0];
#pragma unroll
    for (int e = 1; e < 8; e++) outv = (lane == e) ? acc[e] : outv;
    if (lane < 8) gw[(size_t)b * 8 + lane] = outv / s;
}

// ---------------------------------------------------------------------------
// Mixture: one block per token; thread t handles 4 cols (float4).
// ---------------------------------------------------------------------------
__global__ __launch_bounds__(256) void mixture_kernel(
    const float* __restrict__ gw, const float* __restrict__ eo,
    float* __restrict__ mix)
{
    int b = blockIdx.x, t = threadIdx.x;
    float g[8];
#pragma unroll
    for (int e = 0; e < 8; e++) g[e] = gw[(size_t)b * 8 + e];
    const float4* ep = (const float4*)(eo + (size_t)b * (E_NUM * C_DIM));
    float4 a = make_float4(0.f, 0.f, 0.f, 0.f);
#pragma unroll
    for (int e = 0; e < 8; e++) {
        float4 v = ep[e * 256 + t];
        a.x += g[e] * v.x; a.y += g[e] * v.y;
        a.z += g[e] * v.z; a.w += g[e] * v.w;
    }
    ((float4*)(mix + (size_t)b * C_DIM))[t] = a;
}

// ---------------------------------------------------------------------------
extern "C" void kernel_launch(void* const* d_in, const int* in_sizes, int n_in,
                              void* d_out, int out_size, void* d_ws,
                              size_t ws_size, hipStream_t stream)
{
    const float* x  = (const float*)d_in[0];
    const float* W1 = (const float*)d_in[1];
    const float* b1 = (const float*)d_in[2];
    const float* W2 = (const float*)d_in[3];
    const float* b2 = (const float*)d_in[4];
    const float* Wg = (const float*)d_in[5];
    const float* bg = (const float*)d_in[6];

    // outputs, concatenated flat in return order
    float* mix = (float*)d_out;                        // [B, C]
    float* gw  = mix + (size_t)B_TOK * C_DIM;          // [B, E]
    float* eo  = gw + (size_t)B_TOK * E_NUM;           // [B, E, C]

    const size_t nXB  = (size_t)B_TOK * D_DIM;          // x bf16
    const size_t nW1e = (size_t)H_DIM * D_DIM;          // one expert W1^T
    const size_t nW2e = (size_t)C_DIM * H_DIM;          // one expert W2^T
    const size_t nHBe = (size_t)B_TOK * H_DIM;          // one expert h

    const size_t needBig = (nXB + 8 * nW1e + 8 * nW2e + 8 * nHBe) * sizeof(ushort_t);

    cvt_bf16x4<<<(B_TOK * D_DIM) / 1024, 256, 0, stream>>>(x, (ushort_t*)d_ws);
    gating_kernel<<<B_TOK / 4, 256, 0, stream>>>(x, Wg, bg, gw);

    if (ws_size >= needBig) {
        // ---- mega path: batch everything over experts, 7 dispatches ----
        ushort_t* xb     = (ushort_t*)d_ws;             // B*D
        ushort_t* w1tAll = xb + nXB;                    // 8*H*D
        ushort_t* w2tAll = w1tAll + 8 * nW1e;           // 8*C*H
        ushort_t* hbAll  = w2tAll + 8 * nW2e;           // 8*B*H

        transpose_cvt<<<dim3(H_DIM / 32, D_DIM / 32, 8), dim3(32, 8), 0, stream>>>(
            W1, w1tAll, D_DIM, H_DIM);
        transpose_cvt<<<dim3(C_DIM / 32, H_DIM / 32, 8), dim3(32, 8), 0, stream>>>(
            W2, w2tAll, H_DIM, C_DIM);

        // FC1 mega: h[e] = relu(x @ W1[e] + b1[e])
        // 1D grid 4096; XCD=expert; supertile 4m x 16n sweep.
        gemm256<true><<<dim3(4096), 512, 0, stream>>>(
            xb, w1tAll, b1, hbAll, nullptr, D_DIM, H_DIM,
            0, nW1e, H_DIM, nHBe,
            /*perE=*/512, /*nGrid=*/16, /*supM=*/4);

        // FC2 mega: eo[:,e,:] = h[e] @ W2[e] + b2[e]
        // 1D grid 1024; XCD=expert; m-major n-sweep (h-panel tight reuse).
        gemm256<false><<<dim3(1024), 512, 0, stream>>>(
            hbAll, w2tAll, b2, nullptr, eo, H_DIM, E_NUM * C_DIM,
            nHBe, nW2e, C_DIM, C_DIM,
            /*perE=*/128, /*nGrid=*/4, /*supM=*/1);
    } else {
        // ---- fallback: per-expert loop (small workspace) ----
        ushort_t* xb  = (ushort_t*)d_ws;
        ushort_t* w1t = xb + nXB;
        ushort_t* w2t = w1t + nW1e;
        ushort_t* hb  = w2t + nW2e;

        for (int e = 0; e < E_NUM; e++) {
            transpose_cvt<<<dim3(H_DIM / 32, D_DIM / 32, 1), dim3(32, 8), 0, stream>>>(
                W1 + (size_t)e * D_DIM * H_DIM, w1t, D_DIM, H_DIM);
            gemm256<true><<<dim3(512), 512, 0, stream>>>(
                xb, w1t, b1 + (size_t)e * H_DIM, hb, nullptr, D_DIM, H_DIM,
                0, 0, 0, 0, /*perE=*/512, /*nGrid=*/16, /*supM=*/4);
            transpose_cvt<<<dim3(C_DIM / 32, H_DIM / 32, 1), dim3(32, 8), 0, stream>>>(
                W2 + (size_t)e * H_DIM * C_DIM, w2t, H_DIM, C_DIM);
            gemm_bt_f32<<<dim3(C_DIM / 128, B_TOK / 128), 256, 0, stream>>>(
                hb, w2t, b2 + (size_t)e * C_DIM, eo + (size_t)e * C_DIM,
                B_TOK, C_DIM, H_DIM, E_NUM * C_DIM);
        }
    }

    mixture_kernel<<<B_TOK, 256, 0, stream>>>(gw, eo, mix);
}